// Round 10
// baseline (2684.416 us; speedup 1.0000x reference)
//
#include <hip/hip_runtime.h>
#include <hip/hip_bf16.h>

#define DD 128
#define NREL 8
#define LDHB 1032   // hb row stride (bf16): 2064B = 516 dwords = 4 mod 32 banks -> 2-way (free, m136)
#define BC 16       // cols per block (one 16-row MFMA tile)

typedef float f32x4 __attribute__((ext_vector_type(4)));
typedef short short8 __attribute__((ext_vector_type(8)));

__device__ __forceinline__ float dis_f(float deg) {
    return deg == 0.0f ? 1.0f : rsqrtf(deg);
}

// Fused prep: blocks [0,eb) do in-degree count; blocks [eb, eb+xblk) do x->bf16 convert.
__global__ __launch_bounds__(256) void prep_kernel(const int* __restrict__ ei,
                                                   int* __restrict__ cnt, int E, int eb,
                                                   const float* __restrict__ x,
                                                   __hip_bfloat16* __restrict__ xb, int total4) {
    if (blockIdx.x < (unsigned)eb) {
        int e = blockIdx.x * 256 + threadIdx.x;
        if (e < E) atomicAdd(&cnt[ei[E + e]], 1);
    } else {
        int i = (blockIdx.x - eb) * 256 + threadIdx.x;
        if (i >= total4) return;
        const float4 a = ((const float4*)x)[i];
        __hip_bfloat162 p0 = __float22bfloat162_rn(make_float2(a.x, a.y));
        __hip_bfloat162 p1 = __float22bfloat162_rn(make_float2(a.z, a.w));
        uint2 u;
        u.x = *(unsigned int*)&p0;
        u.y = *(unsigned int*)&p1;
        *(uint2*)&xb[(size_t)i * 4] = u;
    }
}

// 3-phase coalesced scan of ROUNDUP8(cnt) -> pstart[N+1] (+cursor copy, + pad records).
__global__ __launch_bounds__(256) void scanA_kernel(const int* __restrict__ cnt,
                                                    int* __restrict__ bsum, int N) {
    __shared__ int s[256];
    const int i = blockIdx.x * 256 + threadIdx.x;
    int v = (i < N) ? ((cnt[i] + 7) & ~7) : 0;
    s[threadIdx.x] = v;
    __syncthreads();
    for (int off = 1; off < 256; off <<= 1) {
        int add = (threadIdx.x >= off) ? s[threadIdx.x - off] : 0;
        __syncthreads();
        s[threadIdx.x] += add;
        __syncthreads();
    }
    if (threadIdx.x == 255) bsum[blockIdx.x] = s[255];
}

__global__ __launch_bounds__(256) void scanB_kernel(int* __restrict__ bsum,
                                                    int* __restrict__ pstart,
                                                    int nblk, int N) {
    __shared__ int s[256];
    const int t = threadIdx.x;
    int v = (t < nblk) ? bsum[t] : 0;
    s[t] = v;
    __syncthreads();
    for (int off = 1; off < 256; off <<= 1) {
        int add = (t >= off) ? s[t - off] : 0;
        __syncthreads();
        s[t] += add;
        __syncthreads();
    }
    if (t < nblk) bsum[t] = s[t] - v;      // exclusive block base
    if (t == 255) pstart[N] = s[255];      // grand total
}

// scanC also writes the per-col pad records (disjoint from bucket's slots -> order-free).
__global__ __launch_bounds__(256) void scanC_kernel(const int* __restrict__ cnt,
                                                    const int* __restrict__ bsum,
                                                    int* __restrict__ pstart,
                                                    int* __restrict__ cursor,
                                                    uint2* __restrict__ ebuf, int N) {
    __shared__ int s[256];
    const int i = blockIdx.x * 256 + threadIdx.x;
    const int cn = (i < N) ? cnt[i] : 0;
    const int v = (cn + 7) & ~7;
    s[threadIdx.x] = v;
    __syncthreads();
    for (int off = 1; off < 256; off <<= 1) {
        int add = (threadIdx.x >= off) ? s[threadIdx.x - off] : 0;
        __syncthreads();
        s[threadIdx.x] += add;
        __syncthreads();
    }
    if (i < N) {
        const int excl = s[threadIdx.x] - v + bsum[blockIdx.x];
        pstart[i] = excl;
        cursor[i] = excl;
        for (int j = cn; j < v; ++j) ebuf[excl + j] = make_uint2(0u, 0u);
    }
}

// Place edge records sorted by col at padded bases: rec = (et<<16 | row, coef).
__global__ __launch_bounds__(256) void bucket_kernel(const int* __restrict__ ei,
                                                     const int* __restrict__ et,
                                                     const float* __restrict__ ew,
                                                     const int* __restrict__ cnt,
                                                     int* __restrict__ cursor,
                                                     uint2* __restrict__ ebuf, int E) {
    int e = blockIdx.x * blockDim.x + threadIdx.x;
    if (e >= E) return;
    const int row = ei[e], col = ei[E + e];
    const float coef = dis_f((float)cnt[row]) * dis_f((float)cnt[col]) * ew[e];
    const int pos = atomicAdd(&cursor[col], 1);
    ebuf[pos] = make_uint2(((unsigned)et[e] << 16) | (unsigned)row, __float_as_uint(coef));
}

// BT[o][r*128+d] = bf16(W[r][d][o]) via LDS tile transpose (coalesced both sides).
__global__ __launch_bounds__(256) void wtrans_kernel(const float* __restrict__ W1,
                                                     const float* __restrict__ W2,
                                                     __hip_bfloat16* __restrict__ BT1,
                                                     __hip_bfloat16* __restrict__ BT2) {
    __shared__ __hip_bfloat16 tile[128][130];
    const int r = blockIdx.x & 7;
    const float* W = (blockIdx.x >> 3) ? W2 : W1;
    __hip_bfloat16* BT = (blockIdx.x >> 3) ? BT2 : BT1;
    const int o = threadIdx.x & 127;
    const int h = threadIdx.x >> 7;
    for (int d = h; d < DD; d += 2)
        tile[d][o] = __float2bfloat16(W[((size_t)r * DD + d) * DD + o]);
    __syncthreads();
    const int d = threadIdx.x & 127;
    for (int o2 = h; o2 < DD; o2 += 2)
        BT[(size_t)o2 * 1024 + r * DD + d] = tile[d][o2];
}

// Accumulate 4 bf16 (one half-row chunk) into acc[4*ET .. 4*ET+3]; ET/CF scalar per half.
#define PACC(ET, CF, V) do {                                                        \
    const float x0_ = __uint_as_float((V).x << 16);                                 \
    const float x1_ = __uint_as_float((V).x & 0xffff0000u);                         \
    const float x2_ = __uint_as_float((V).y << 16);                                 \
    const float x3_ = __uint_as_float((V).y & 0xffff0000u);                         \
    const float c_ = (CF);                                                          \
    switch (ET) {                                                                   \
        case 0: acc[0] +=c_*x0_; acc[1] +=c_*x1_; acc[2] +=c_*x2_; acc[3] +=c_*x3_; break; \
        case 1: acc[4] +=c_*x0_; acc[5] +=c_*x1_; acc[6] +=c_*x2_; acc[7] +=c_*x3_; break; \
        case 2: acc[8] +=c_*x0_; acc[9] +=c_*x1_; acc[10]+=c_*x2_; acc[11]+=c_*x3_; break; \
        case 3: acc[12]+=c_*x0_; acc[13]+=c_*x1_; acc[14]+=c_*x2_; acc[15]+=c_*x3_; break; \
        case 4: acc[16]+=c_*x0_; acc[17]+=c_*x1_; acc[18]+=c_*x2_; acc[19]+=c_*x3_; break; \
        case 5: acc[20]+=c_*x0_; acc[21]+=c_*x1_; acc[22]+=c_*x2_; acc[23]+=c_*x3_; break; \
        case 6: acc[24]+=c_*x0_; acc[25]+=c_*x1_; acc[26]+=c_*x2_; acc[27]+=c_*x3_; break; \
        default: acc[28]+=c_*x0_; acc[29]+=c_*x1_; acc[30]+=c_*x2_; acc[31]+=c_*x3_; break; \
    } } while (0)

// Fused per-layer: scalar-load records -> PAIRED gather (2 rows per dwordx2 VMEM
// instruction: lanes 0-31 = row A, lanes 32-63 = row B) -> shfl merge -> LDS h tile
// -> MFMA with BT. Block = 16 cols, 8 waves; 2 cols per wave.
template<int LAYER>
__global__ __launch_bounds__(512, 6) void fused_kernel(const __hip_bfloat16* __restrict__ srcb,
                                                       const uint2* __restrict__ ebuf,
                                                       const int* __restrict__ pstart, // [N+1]
                                                       const __hip_bfloat16* __restrict__ BT,
                                                       const float* __restrict__ bias,
                                                       const __hip_bfloat16* __restrict__ xbp,
                                                       __hip_bfloat16* __restrict__ z1b,
                                                       float* __restrict__ out, int N) {
    __shared__ __hip_bfloat16 hb[BC][LDHB];
    const int tid = threadIdx.x;
    const int w = tid >> 6, l = tid & 63;
    const int c0 = blockIdx.x * BC;
    const int j = l & 31;          // d-chunk index: this lane covers d = 4j..4j+3
    const int H = l >> 5;          // half: 0 -> even edge of pair, 1 -> odd edge
    const unsigned laneoff = (unsigned)j * 8u;

    #pragma unroll
    for (int q = 0; q < 2; ++q) {
        const int c = c0 + 2 * w + q;
        float acc[32];
        #pragma unroll
        for (int i = 0; i < 32; ++i) acc[i] = 0.f;
        if (c < N) {
            const int beg = __builtin_amdgcn_readfirstlane(pstart[c]);
            const int end = __builtin_amdgcn_readfirstlane(pstart[c + 1]);
            // padded segment: (end-beg) % 8 == 0; 4 row-pairs per batch
            for (int e = beg; e < end; e += 8) {
                unsigned ms[8]; float cf[8];
                #pragma unroll
                for (int i = 0; i < 8; ++i) {
                    const uint2 rr = ebuf[e + i];          // uniform addr -> scalar load
                    ms[i] = (unsigned)__builtin_amdgcn_readfirstlane((int)rr.x);
                    cf[i] = __uint_as_float((unsigned)__builtin_amdgcn_readfirstlane((int)rr.y));
                }
                uint2 vv[4];
                #pragma unroll
                for (int p = 0; p < 4; ++p) {
                    const unsigned offA = (ms[2 * p] & 0xffffu) << 8;      // row * 256B
                    const unsigned offB = (ms[2 * p + 1] & 0xffffu) << 8;
                    const unsigned off = (H ? offB : offA) + laneoff;
                    vv[p] = *(const uint2*)((const char*)srcb + off);      // 1 VMEM, 2 rows
                }
                #pragma unroll
                for (int p = 0; p < 4; ++p) {
                    const int etA = (int)(ms[2 * p] >> 16);
                    const int etB = (int)(ms[2 * p + 1] >> 16);
                    if (H == 0) { PACC(etA, cf[2 * p], vv[p]); }
                    else        { PACC(etB, cf[2 * p + 1], vv[p]); }
                }
            }
        }
        // merge even/odd halves: lane (H,j) <-> lane (H^1,j)
        #pragma unroll
        for (int i = 0; i < 32; ++i) acc[i] += __shfl_xor(acc[i], 32);
        // h row -> LDS (bf16): H=0 writes relations 0..3, H=1 writes 4..7
        const int m = 2 * w + q;
        #pragma unroll
        for (int rr = 0; rr < 4; ++rr) {
            float a0, a1, a2, a3;
            if (H == 0) { a0 = acc[4*rr]; a1 = acc[4*rr+1]; a2 = acc[4*rr+2]; a3 = acc[4*rr+3]; }
            else { a0 = acc[16+4*rr]; a1 = acc[16+4*rr+1]; a2 = acc[16+4*rr+2]; a3 = acc[16+4*rr+3]; }
            __hip_bfloat162 pA = __float22bfloat162_rn(make_float2(a0, a1));
            __hip_bfloat162 pB = __float22bfloat162_rn(make_float2(a2, a3));
            uint2 u;
            u.x = *(unsigned int*)&pA;
            u.y = *(unsigned int*)&pB;
            *(uint2*)&hb[m][(4 * H + rr) * DD + 4 * j] = u;
        }
    }
    __syncthreads();

    // ---- MFMA: rows 0-15 x o-slice [w*16, w*16+16), K=1024
    const int lk = (l >> 4) * 8;
    const int lr = l & 15;
    f32x4 acc0 = {0.f, 0.f, 0.f, 0.f};
    const __hip_bfloat16* bt = BT + (size_t)(w * 16 + lr) * 1024 + lk;
    const __hip_bfloat16* h0 = &hb[lr][lk];
    #pragma unroll 8
    for (int k0 = 0; k0 < 1024; k0 += 32) {
        const short8 b  = *(const short8*)(bt + k0);
        const short8 a0 = *(const short8*)(h0 + k0);
        acc0 = __builtin_amdgcn_mfma_f32_16x16x32_bf16(a0, b, acc0, 0, 0, 0);
    }

    // ---- epilogue: D row=(l>>4)*4+q (graph col), col=l&15 (o)
    const int rbase = (l >> 4) * 4;
    const int o = w * 16 + lr;
    const float bv = bias[o];
    #pragma unroll
    for (int q = 0; q < 4; ++q) {
        const int c = c0 + rbase + q;
        if (c >= N) continue;
        const size_t idx = (size_t)c * DD + o;
        float v = acc0[q] + bv;
        if (LAYER == 1) {
            v = v >= 0.f ? v : 0.01f * v;   // leaky_relu
            z1b[idx] = __float2bfloat16(v);
        } else {
            const float z1v = __bfloat162float(z1b[idx]);
            const float xv2 = __bfloat162float(xbp[idx]);   // bf16 x: halves epilogue fetch
            out[idx] = (xv2 + z1v + v) * 0.25f;                  // z_star
            out[(size_t)N * DD + idx] = (z1v + v) * (1.f / 3.f); // z_sharp
        }
    }
}

extern "C" void kernel_launch(void* const* d_in, const int* in_sizes, int n_in,
                              void* d_out, int out_size, void* d_ws, size_t ws_size,
                              hipStream_t stream) {
    const float* x  = (const float*)d_in[0];
    const int*   ei = (const int*)d_in[1];
    const int*   et = (const int*)d_in[2];
    const float* ew = (const float*)d_in[3];
    const float* W1 = (const float*)d_in[4];
    const float* b1 = (const float*)d_in[5];
    const float* W2 = (const float*)d_in[6];
    const float* b2 = (const float*)d_in[7];

    const int N = in_sizes[0] / DD;
    const int E = in_sizes[3];
    float* out = (float*)d_out;

    // ws: cnt[N] | pstart[N+16] | cursor[N] | bsum[256] | BT1 | BT2 | ebuf[E+8N] | xb | z1b
    char* w = (char*)d_ws;
    int* cnt = (int*)w;                 w += (size_t)N * 4;
    int* pstart = (int*)w;              w += (size_t)(N + 16) * 4;
    int* cursor = (int*)w;              w += (size_t)N * 4;
    int* bsum = (int*)w;                w += 256 * 4;
    __hip_bfloat16* BT1 = (__hip_bfloat16*)w;  w += (size_t)DD * NREL * DD * 2;
    __hip_bfloat16* BT2 = (__hip_bfloat16*)w;  w += (size_t)DD * NREL * DD * 2;
    uint2* ebuf = (uint2*)w;            w += ((size_t)E + 8 * (size_t)N) * 8;
    __hip_bfloat16* xb = (__hip_bfloat16*)w;   w += (size_t)N * DD * 2;
    __hip_bfloat16* z1b = (__hip_bfloat16*)w;

    hipMemsetAsync(cnt, 0, (size_t)N * 4, stream);

    const int eb = (E + 255) / 256;
    const int t4 = N * DD / 4;
    const int xblk = (t4 + 255) / 256;
    const int nscb = (N + 255) / 256;   // <= 256 required (N <= 65536)

    prep_kernel<<<eb + xblk, 256, 0, stream>>>(ei, cnt, E, eb, x, xb, t4);
    wtrans_kernel<<<16, 256, 0, stream>>>(W1, W2, BT1, BT2);
    scanA_kernel<<<nscb, 256, 0, stream>>>(cnt, bsum, N);
    scanB_kernel<<<1, 256, 0, stream>>>(bsum, pstart, nscb, N);
    scanC_kernel<<<nscb, 256, 0, stream>>>(cnt, bsum, pstart, cursor, ebuf, N);
    bucket_kernel<<<eb, 256, 0, stream>>>(ei, et, ew, cnt, cursor, ebuf, E);

    const int nb = (N + BC - 1) / BC;
    fused_kernel<1><<<nb, 512, 0, stream>>>(xb,  ebuf, pstart, BT1, b1, xb, z1b, out, N);
    fused_kernel<2><<<nb, 512, 0, stream>>>(z1b, ebuf, pstart, BT2, b2, xb, z1b, out, N);
}

// Round 11
// 343.738 us; speedup vs baseline: 7.8095x; 7.8095x over previous
//
#include <hip/hip_runtime.h>
#include <hip/hip_bf16.h>

#define DD 128
#define NREL 8
#define LDHB 1032   // hb row stride (bf16): 2064B = 516 dwords = 4 mod 32 banks -> 2-way (free, m136)
#define BC 16       // cols per block (one 16-row MFMA tile)
#define NW 8        // row windows (row>>13): 8192 rows * 256B = 2MB bf16, fits 4MB per-XCD L2

typedef float f32x4 __attribute__((ext_vector_type(4)));
typedef short short8 __attribute__((ext_vector_type(8)));

__device__ __forceinline__ float dis_f(float deg) {
    return deg == 0.0f ? 1.0f : rsqrtf(deg);
}

// Fused prep: blocks [0,eb) count per (col, row-window); blocks [eb,eb+xblk) do x->bf16.
__global__ __launch_bounds__(256) void prep_kernel(const int* __restrict__ ei,
                                                   int* __restrict__ wofs, int E, int eb,
                                                   const float* __restrict__ x,
                                                   __hip_bfloat16* __restrict__ xb, int total4) {
    if (blockIdx.x < (unsigned)eb) {
        int e = blockIdx.x * 256 + threadIdx.x;
        if (e < E) {
            const int row = ei[e], col = ei[E + e];
            atomicAdd(&wofs[col * NW + (row >> 13)], 1);
        }
    } else {
        int i = (blockIdx.x - eb) * 256 + threadIdx.x;
        if (i >= total4) return;
        const float4 a = ((const float4*)x)[i];
        __hip_bfloat162 p0 = __float22bfloat162_rn(make_float2(a.x, a.y));
        __hip_bfloat162 p1 = __float22bfloat162_rn(make_float2(a.z, a.w));
        uint2 u;
        u.x = *(unsigned int*)&p0;
        u.y = *(unsigned int*)&p1;
        *(uint2*)&xb[(size_t)i * 4] = u;
    }
}

// 3-phase coalesced scan over per-col padded sizes (col size = sum of its NW window counts).
__global__ __launch_bounds__(256) void scanA_kernel(const int* __restrict__ wofs,
                                                    int* __restrict__ bsum, int N) {
    __shared__ int s[256];
    const int i = blockIdx.x * 256 + threadIdx.x;
    int padded = 0;
    if (i < N) {
        int t = 0;
        #pragma unroll
        for (int k = 0; k < NW; ++k) t += wofs[i * NW + k];
        padded = (t + 7) & ~7;
    }
    s[threadIdx.x] = padded;
    __syncthreads();
    for (int off = 1; off < 256; off <<= 1) {
        int add = (threadIdx.x >= off) ? s[threadIdx.x - off] : 0;
        __syncthreads();
        s[threadIdx.x] += add;
        __syncthreads();
    }
    if (threadIdx.x == 255) bsum[blockIdx.x] = s[255];
}

__global__ __launch_bounds__(256) void scanB_kernel(int* __restrict__ bsum,
                                                    int* __restrict__ pstart,
                                                    int nblk, int N) {
    __shared__ int s[256];
    const int t = threadIdx.x;
    int v = (t < nblk) ? bsum[t] : 0;
    s[t] = v;
    __syncthreads();
    for (int off = 1; off < 256; off <<= 1) {
        int add = (t >= off) ? s[t - off] : 0;
        __syncthreads();
        s[t] += add;
        __syncthreads();
    }
    if (t < nblk) bsum[t] = s[t] - v;      // exclusive block base
    if (t == 255) pstart[N] = s[255];      // grand total
}

// scanC: per col -> pstart, true degree cnt, per-window cursors (in wofs), pad records.
__global__ __launch_bounds__(256) void scanC_kernel(int* __restrict__ wofs,
                                                    const int* __restrict__ bsum,
                                                    int* __restrict__ pstart,
                                                    int* __restrict__ cnt,
                                                    uint2* __restrict__ ebuf, int N) {
    __shared__ int s[256];
    const int i = blockIdx.x * 256 + threadIdx.x;
    int cw[NW];
    int tot = 0;
    if (i < N) {
        #pragma unroll
        for (int k = 0; k < NW; ++k) { cw[k] = wofs[i * NW + k]; tot += cw[k]; }
    }
    const int padded = (tot + 7) & ~7;
    s[threadIdx.x] = padded;
    __syncthreads();
    for (int off = 1; off < 256; off <<= 1) {
        int add = (threadIdx.x >= off) ? s[threadIdx.x - off] : 0;
        __syncthreads();
        s[threadIdx.x] += add;
        __syncthreads();
    }
    if (i < N) {
        const int excl = s[threadIdx.x] - padded + bsum[blockIdx.x];
        pstart[i] = excl;
        cnt[i] = tot;
        int run = excl;
        #pragma unroll
        for (int k = 0; k < NW; ++k) { wofs[i * NW + k] = run; run += cw[k]; }
        for (int j = tot; j < padded; ++j) ebuf[excl + j] = make_uint2(0u, 0u);
    }
}

// Place records sorted by (col, row-window): rec = (et<<16 | row, coef).
__global__ __launch_bounds__(256) void bucket_kernel(const int* __restrict__ ei,
                                                     const int* __restrict__ et,
                                                     const float* __restrict__ ew,
                                                     const int* __restrict__ cnt,
                                                     int* __restrict__ wofs,
                                                     uint2* __restrict__ ebuf, int E) {
    int e = blockIdx.x * blockDim.x + threadIdx.x;
    if (e >= E) return;
    const int row = ei[e], col = ei[E + e];
    const float coef = dis_f((float)cnt[row]) * dis_f((float)cnt[col]) * ew[e];
    const int pos = atomicAdd(&wofs[col * NW + (row >> 13)], 1);
    ebuf[pos] = make_uint2(((unsigned)et[e] << 16) | (unsigned)row, __float_as_uint(coef));
}

// BT[o][r*128+d] = bf16(W[r][d][o]) via LDS tile transpose (coalesced both sides).
__global__ __launch_bounds__(256) void wtrans_kernel(const float* __restrict__ W1,
                                                     const float* __restrict__ W2,
                                                     __hip_bfloat16* __restrict__ BT1,
                                                     __hip_bfloat16* __restrict__ BT2) {
    __shared__ __hip_bfloat16 tile[128][130];
    const int r = blockIdx.x & 7;
    const float* W = (blockIdx.x >> 3) ? W2 : W1;
    __hip_bfloat16* BT = (blockIdx.x >> 3) ? BT2 : BT1;
    const int o = threadIdx.x & 127;
    const int h = threadIdx.x >> 7;
    for (int d = h; d < DD; d += 2)
        tile[d][o] = __float2bfloat16(W[((size_t)r * DD + d) * DD + o]);
    __syncthreads();
    const int d = threadIdx.x & 127;
    for (int o2 = h; o2 < DD; o2 += 2)
        BT[(size_t)o2 * 1024 + r * DD + d] = tile[d][o2];
}

// Fused per-layer: scalar-load records -> 8-deep register gather (one col at a time,
// single acc bank: no spills) -> LDS h tile -> MFMA with BT. Block = 16 cols, 8 waves.
// Identical to the proven round-9 kernel (VGPR 32, no scratch).
template<int LAYER>
__global__ __launch_bounds__(512, 8) void fused_kernel(const __hip_bfloat16* __restrict__ srcb,
                                                       const uint2* __restrict__ ebuf,
                                                       const int* __restrict__ pstart, // [N+1]
                                                       const __hip_bfloat16* __restrict__ BT,
                                                       const float* __restrict__ bias,
                                                       const __hip_bfloat16* __restrict__ xbp,
                                                       __hip_bfloat16* __restrict__ z1b,
                                                       float* __restrict__ out, int N) {
    __shared__ __hip_bfloat16 hb[BC][LDHB];
    const int tid = threadIdx.x;
    const int w = tid >> 6, l = tid & 63;
    const int c0 = blockIdx.x * BC;

    #pragma unroll
    for (int q = 0; q < 2; ++q) {
        const int c = c0 + 2 * w + q;
        float acc[16];
        #pragma unroll
        for (int i = 0; i < 16; ++i) acc[i] = 0.f;
        if (c < N) {
            const int beg = __builtin_amdgcn_readfirstlane(pstart[c]);
            const int end = __builtin_amdgcn_readfirstlane(pstart[c + 1]);
            // padded segment: (end-beg) % 8 == 0; full 8-batches only
            for (int e = beg; e < end; e += 8) {
                unsigned ms[8]; float cf[8]; unsigned vv[8];
                #pragma unroll
                for (int i = 0; i < 8; ++i) {
                    const uint2 rr = ebuf[e + i];          // uniform addr -> scalar load
                    ms[i] = (unsigned)__builtin_amdgcn_readfirstlane((int)rr.x);
                    cf[i] = __uint_as_float((unsigned)__builtin_amdgcn_readfirstlane((int)rr.y));
                }
                #pragma unroll
                for (int i = 0; i < 8; ++i)
                    vv[i] = *(const unsigned*)&srcb[(size_t)(ms[i] & 0xffffu) * DD + 2 * l];
                #pragma unroll
                for (int i = 0; i < 8; ++i) {
                    const float xl = __uint_as_float(vv[i] << 16);
                    const float xh = __uint_as_float(vv[i] & 0xffff0000u);
                    const float cf_ = cf[i];
                    switch (ms[i] >> 16) {                 // scalar branch, 2 accs touched
                        case 0: acc[0]  += cf_*xl; acc[1]  += cf_*xh; break;
                        case 1: acc[2]  += cf_*xl; acc[3]  += cf_*xh; break;
                        case 2: acc[4]  += cf_*xl; acc[5]  += cf_*xh; break;
                        case 3: acc[6]  += cf_*xl; acc[7]  += cf_*xh; break;
                        case 4: acc[8]  += cf_*xl; acc[9]  += cf_*xh; break;
                        case 5: acc[10] += cf_*xl; acc[11] += cf_*xh; break;
                        case 6: acc[12] += cf_*xl; acc[13] += cf_*xh; break;
                        default: acc[14] += cf_*xl; acc[15] += cf_*xh; break;
                    }
                }
            }
        }
        // h row -> LDS (bf16); frees acc for next col
        const int m = 2 * w + q;
        #pragma unroll
        for (int r = 0; r < NREL; ++r) {
            __hip_bfloat162 p = __float22bfloat162_rn(make_float2(acc[2 * r], acc[2 * r + 1]));
            *(unsigned int*)&hb[m][r * DD + 2 * l] = *(unsigned int*)&p;
        }
    }
    __syncthreads();

    // ---- MFMA: rows 0-15 x o-slice [w*16, w*16+16), K=1024
    const int lk = (l >> 4) * 8;
    const int lr = l & 15;
    f32x4 acc0 = {0.f, 0.f, 0.f, 0.f};
    const __hip_bfloat16* bt = BT + (size_t)(w * 16 + lr) * 1024 + lk;
    const __hip_bfloat16* h0 = &hb[lr][lk];
    #pragma unroll 8
    for (int k0 = 0; k0 < 1024; k0 += 32) {
        const short8 b  = *(const short8*)(bt + k0);
        const short8 a0 = *(const short8*)(h0 + k0);
        acc0 = __builtin_amdgcn_mfma_f32_16x16x32_bf16(a0, b, acc0, 0, 0, 0);
    }

    // ---- epilogue: D row=(l>>4)*4+q (graph col), col=l&15 (o)
    const int rbase = (l >> 4) * 4;
    const int o = w * 16 + lr;
    const float bv = bias[o];
    #pragma unroll
    for (int q = 0; q < 4; ++q) {
        const int c = c0 + rbase + q;
        if (c >= N) continue;
        const size_t idx = (size_t)c * DD + o;
        float v = acc0[q] + bv;
        if (LAYER == 1) {
            v = v >= 0.f ? v : 0.01f * v;   // leaky_relu
            z1b[idx] = __float2bfloat16(v);
        } else {
            const float z1v = __bfloat162float(z1b[idx]);
            const float xv2 = __bfloat162float(xbp[idx]);   // bf16 x: halves epilogue fetch
            out[idx] = (xv2 + z1v + v) * 0.25f;                  // z_star
            out[(size_t)N * DD + idx] = (z1v + v) * (1.f / 3.f); // z_sharp
        }
    }
}

extern "C" void kernel_launch(void* const* d_in, const int* in_sizes, int n_in,
                              void* d_out, int out_size, void* d_ws, size_t ws_size,
                              hipStream_t stream) {
    const float* x  = (const float*)d_in[0];
    const int*   ei = (const int*)d_in[1];
    const int*   et = (const int*)d_in[2];
    const float* ew = (const float*)d_in[3];
    const float* W1 = (const float*)d_in[4];
    const float* b1 = (const float*)d_in[5];
    const float* W2 = (const float*)d_in[6];
    const float* b2 = (const float*)d_in[7];

    const int N = in_sizes[0] / DD;
    const int E = in_sizes[3];
    float* out = (float*)d_out;

    // ws: cnt[N] | pstart[N+16] | wofs[N*NW] | bsum[256] | BT1 | BT2 | ebuf[E+8N] | xb | z1b
    char* w = (char*)d_ws;
    int* cnt = (int*)w;                 w += (size_t)N * 4;
    int* pstart = (int*)w;              w += (size_t)(N + 16) * 4;
    int* wofs = (int*)w;                w += (size_t)N * NW * 4;
    int* bsum = (int*)w;                w += 256 * 4;
    __hip_bfloat16* BT1 = (__hip_bfloat16*)w;  w += (size_t)DD * NREL * DD * 2;
    __hip_bfloat16* BT2 = (__hip_bfloat16*)w;  w += (size_t)DD * NREL * DD * 2;
    uint2* ebuf = (uint2*)w;            w += ((size_t)E + 8 * (size_t)N) * 8;
    __hip_bfloat16* xb = (__hip_bfloat16*)w;   w += (size_t)N * DD * 2;
    __hip_bfloat16* z1b = (__hip_bfloat16*)w;

    hipMemsetAsync(wofs, 0, (size_t)N * NW * 4, stream);

    const int eb = (E + 255) / 256;
    const int t4 = N * DD / 4;
    const int xblk = (t4 + 255) / 256;
    const int nscb = (N + 255) / 256;   // <= 256 required (N <= 65536)

    prep_kernel<<<eb + xblk, 256, 0, stream>>>(ei, wofs, E, eb, x, xb, t4);
    wtrans_kernel<<<16, 256, 0, stream>>>(W1, W2, BT1, BT2);
    scanA_kernel<<<nscb, 256, 0, stream>>>(wofs, bsum, N);
    scanB_kernel<<<1, 256, 0, stream>>>(bsum, pstart, nscb, N);
    scanC_kernel<<<nscb, 256, 0, stream>>>(wofs, bsum, pstart, cnt, ebuf, N);
    bucket_kernel<<<eb, 256, 0, stream>>>(ei, et, ew, cnt, wofs, ebuf, E);

    const int nb = (N + BC - 1) / BC;
    fused_kernel<1><<<nb, 512, 0, stream>>>(xb,  ebuf, pstart, BT1, b1, xb, z1b, out, N);
    fused_kernel<2><<<nb, 512, 0, stream>>>(z1b, ebuf, pstart, BT2, b2, xb, z1b, out, N);
}